// Round 8
// baseline (275.383 us; speedup 1.0000x reference)
//
#include <hip/hip_runtime.h>

// FractalEmbedding: out[b,l,d] = scale * sum_f feats(token)[f] * W[d,f]
// feats = 8-step Julia iteration on c_table[token], interleaved (zr,zi).
//
// B=8, L=8192 -> 65536 tokens; D=1024; 16 features. Output = 268 MB f32.
// Fill kernel proves 6.5 TB/s writes on this machine; six structurally
// different kernels (serial / pipelined / packed / no-loop / LDS-shared)
// all plateau at ~104-126 us implied kernel time (~2.5 TB/s). Issue rate,
// gather latency, store-reuse stalls, and compute redundancy are each
// falsified as the cap. The one constant: all waves march in LOCKSTEP
// through token offsets, so the whole chip writes the same 4KB-aligned
// offset phase simultaneously (potential HBM channel hotspotting).
//
// v7 = v6 (compute feats once per block, share via LDS) plus:
//   * per-block token-phase rotation: block b starts its store loop at
//     tk0=(b*37)&63 and wraps -> cross-block store phases decorrelated.
//     Pure iteration-order permutation: outputs bit-identical.
//   * packed v2f dot accumulation (32 pk-FMAs instead of 64 scalar);
//     per-output-dim FMA order unchanged (ascending features).
// Grid 1024 x 256 (64 tokens/block), W in registers, scale folded.

#define STEPS 8
#define NFEAT (2 * STEPS)
#define EMBED 1024
#define NTOK (8 * 8192)
#define TOKB 64                  // tokens per block
#define BLOCK 256                // thread t -> output dims 4t..4t+3
#define GRID (NTOK / TOKB)       // 1024 blocks, exact

typedef float v2f __attribute__((ext_vector_type(2)));
typedef float v4f __attribute__((ext_vector_type(4)));

__global__ __launch_bounds__(BLOCK) void FractalEmbedding_30365418782757_kernel(
    const int* __restrict__ tok,
    const float* __restrict__ ctab,   // (V, 2)
    const float* __restrict__ W,      // (1024, 16) row-major
    const float* __restrict__ scale_p,
    float* __restrict__ out)          // (NTOK, 1024)
{
    __shared__ float feats_lds[TOKB * NFEAT];   // 4 KB

    const int t  = threadIdx.x;
    const int b  = blockIdx.x;
    const int g0 = b * TOKB;                    // first token of this block
    const float s = *scale_p;

    // ---- phase 1: wave 0 computes all 64 tokens' features, one per lane ----
    if (t < TOKB) {
        const int id = tok[g0 + t];                                 // coalesced
        const float2 c = reinterpret_cast<const float2*>(ctab)[id]; // gather
        float f[NFEAT];
        float zr = 0.0f, zi = 0.0f;
#pragma unroll
        for (int st = 0; st < STEPS; ++st) {
            float nzr = zr * zr - zi * zi + c.x;
            float nzi = 2.0f * zr * zi + c.y;
            zr = nzr; zi = nzi;
            f[2 * st]     = zr;
            f[2 * st + 1] = zi;
        }
        v4f* dst = reinterpret_cast<v4f*>(feats_lds + t * NFEAT);
#pragma unroll
        for (int q = 0; q < 4; ++q)
            dst[q] = (v4f){f[4 * q], f[4 * q + 1], f[4 * q + 2], f[4 * q + 3]};
    }

    // W rows for dims 4t..4t+3, pair-interleaved for packed FMA; scale folded.
    // wp[k][0] = {W[4t][k],  W[4t+1][k]} * s ; wp[k][1] = {W[4t+2][k], W[4t+3][k]} * s
    v2f wp[NFEAT][2];
#pragma unroll
    for (int r = 0; r < 4; ++r) {
        const float4* wrow = reinterpret_cast<const float4*>(W + (size_t)(4 * t + r) * NFEAT);
#pragma unroll
        for (int q = 0; q < 4; ++q) {
            float4 v = wrow[q];
            float vv[4] = {v.x, v.y, v.z, v.w};
#pragma unroll
            for (int e = 0; e < 4; ++e)
                wp[4 * q + e][r >> 1][r & 1] = vv[e] * s;
        }
    }

    __syncthreads();

    // ---- phase 2: dot + store, token loop rotated per block ----
    const v4f* fp = reinterpret_cast<const v4f*>(feats_lds);
    v4f* obase = reinterpret_cast<v4f*>(out + (size_t)g0 * EMBED) + t;
    const int tk0 = (b * 37) & (TOKB - 1);      // decorrelate cross-block phase

#pragma unroll 2
    for (int j = 0; j < TOKB; ++j) {
        const int tk = (tk0 + j) & (TOKB - 1);

        // 4 broadcast LDS reads: 16 features of token tk.
        v4f f0 = fp[tk * 4 + 0];
        v4f f1 = fp[tk * 4 + 1];
        v4f f2 = fp[tk * 4 + 2];
        v4f f3 = fp[tk * 4 + 3];
        float fk[NFEAT] = {f0.x, f0.y, f0.z, f0.w,  f1.x, f1.y, f1.z, f1.w,
                           f2.x, f2.y, f2.z, f2.w,  f3.x, f3.y, f3.z, f3.w};

        v2f acc01 = (v2f){0.f, 0.f};   // dims 4t, 4t+1
        v2f acc23 = (v2f){0.f, 0.f};   // dims 4t+2, 4t+3
#pragma unroll
        for (int k = 0; k < NFEAT; ++k) {        // ascending-feature order
            acc01 += fk[k] * wp[k][0];
            acc23 += fk[k] * wp[k][1];
        }

        v4f o = (v4f){acc01.x, acc01.y, acc23.x, acc23.y};
        obase[(size_t)tk * (EMBED / 4)] = o;     // 16 B/lane, full 4KB row/block
    }
}

extern "C" void kernel_launch(void* const* d_in, const int* in_sizes, int n_in,
                              void* d_out, int out_size, void* d_ws, size_t ws_size,
                              hipStream_t stream) {
    const int*   tok   = (const int*)d_in[0];
    const float* ctab  = (const float*)d_in[1];
    const float* W     = (const float*)d_in[2];
    const float* scale = (const float*)d_in[3];
    float*       out   = (float*)d_out;

    FractalEmbedding_30365418782757_kernel<<<GRID, BLOCK, 0, stream>>>(tok, ctab, W, scale, out);
}

// Round 9
// 267.210 us; speedup vs baseline: 1.0306x; 1.0306x over previous
//
#include <hip/hip_runtime.h>

// FractalEmbedding: out[b,l,d] = scale * sum_f feats(token)[f] * W[d,f]
// feats = 8-step Julia iteration on c_table[token], interleaved (zr,zi).
//
// B=8, L=8192 -> 65536 tokens; D=1024; 16 features. Output = 256 MiB f32.
// BEST-MEASURED VARIANT (round 4: 266.5 us bench). Reverted to after the
// falsification ladder below; kept as final.
//
// Falsification ledger (bench band 266-289 us across all of these):
//   1. serial token loop        -> 4-token batch + id prefetch   (-25 us)
//   2. exposed gather latency   -> depth-2 c-value pipeline      (-6 us)
//   3. VGPR spill / NT recycle  -> 512thr x 2rows, plain stores  (-10 us, best)
//   4. store->reg-reuse stalls  -> no-loop fire-and-exit         (+22 us, worse)
//   5. redundant Julia VALU     -> LDS-shared feats (2.3x cut)   (flat)
//   6. scalar FMA issue rate    -> packed v2f (v_pk_fma_f32)     (flat)
//   7. HBM channel lockstep     -> per-block store-phase rotate  (flat)
// The timed region also contains a harness-owned 1 GiB fill (~163 us @ 82%
// HBM peak) that no kernel change can touch. Remaining kernel share ~100 us
// is insensitive to every mechanism above; structure below is at its floor.
//
// Structure: 512 threads/block, thread t -> output dims 2t,2t+1 (W pair-
// interleaved in 32 VGPRs, scale folded; scale==1.0 -> bit-identical).
// 4 tokens/iter as 2 packed v2f Julia chains, dot fused in ascending-feature
// order; c-values pipelined one iter ahead, token ids two ahead; plain
// dwordx2 stores (coalesced 512B/wave-store).

#define STEPS 8
#define NFEAT (2 * STEPS)
#define EMBED 1024
#define NTOK (8 * 8192)
#define TB 4                    // tokens per iteration
#define NGRP (NTOK / TB)        // 16384 groups
#define BLOCK 512               // thread t -> output dims 2t, 2t+1
#define GRID 2048               // NGRP/GRID = 8 iterations per block, exact
#define ITERS (NGRP / GRID)

typedef float v2f __attribute__((ext_vector_type(2)));

__global__ __launch_bounds__(BLOCK) void FractalEmbedding_30365418782757_kernel(
    const int* __restrict__ tok,
    const float* __restrict__ ctab,   // (V, 2)
    const float* __restrict__ W,      // (1024, 16) row-major
    const float* __restrict__ scale_p,
    float* __restrict__ out)          // (NTOK, 1024)
{
    const int t = threadIdx.x;        // dims 2t, 2t+1
    const float s = *scale_p;

    // Two W rows per thread, pair-interleaved for packed FMA; scale folded.
    v2f w2[NFEAT];                    // w2[k] = { W[2t][k], W[2t+1][k] } * s
    {
        const float4* r0 = reinterpret_cast<const float4*>(W + (size_t)(2 * t)     * NFEAT);
        const float4* r1 = reinterpret_cast<const float4*>(W + (size_t)(2 * t + 1) * NFEAT);
#pragma unroll
        for (int q = 0; q < 4; ++q) {
            float4 a = r0[q];
            float4 b = r1[q];
            w2[4 * q + 0] = (v2f){a.x * s, b.x * s};
            w2[4 * q + 1] = (v2f){a.y * s, b.y * s};
            w2[4 * q + 2] = (v2f){a.z * s, b.z * s};
            w2[4 * q + 3] = (v2f){a.w * s, b.w * s};
        }
    }

    const int4*   tok4 = reinterpret_cast<const int4*>(tok);
    const float2* c2   = reinterpret_cast<const float2*>(ctab);
    const int     b    = blockIdx.x;

    // ---- pipeline prologue: c for iter 0, ids for iter 1 ----
    int4 ids0 = tok4[b];
    float2 ca = c2[ids0.x];
    float2 cb = c2[ids0.y];
    float2 cc = c2[ids0.z];
    float2 cd = c2[ids0.w];
    int gi1 = b + GRID;
    int4 ids = tok4[(gi1 < NGRP) ? gi1 : (NGRP - 1)];

    for (int i = 0; i < ITERS; ++i) {
        const int g = b + i * GRID;

        // Issue next iteration's gathers now (ids already resident) ...
        float2 n0 = c2[ids.x];
        float2 n1 = c2[ids.y];
        float2 n2 = c2[ids.z];
        float2 n3 = c2[ids.w];
        // ... and ids for iteration i+2 (clamped; redundant at the tail).
        int gi2 = g + 2 * GRID;
        int4 nids = tok4[(gi2 < NGRP) ? gi2 : (NGRP - 1)];

        // ---- compute iteration i, packed across token pairs ----
        // chains A = tokens {0,1}, B = tokens {2,3}
        v2f cxA = (v2f){ca.x, cb.x}, cyA = (v2f){ca.y, cb.y};
        v2f cxB = (v2f){cc.x, cd.x}, cyB = (v2f){cc.y, cd.y};
        v2f zrA = (v2f){0.f, 0.f}, ziA = zrA, zrB = zrA, ziB = zrA;
        v2f acc0 = zrA, acc1 = zrA, acc2 = zrA, acc3 = zrA;  // per-token {row2t,row2t+1}

#pragma unroll
        for (int st = 0; st < STEPS; ++st) {
            v2f aA = zrA * zrA - ziA * ziA + cxA;
            v2f bA = 2.0f * zrA * ziA + cyA;
            v2f aB = zrB * zrB - ziB * ziB + cxB;
            v2f bB = 2.0f * zrB * ziB + cyB;
            zrA = aA; ziA = bA; zrB = aB; ziB = bB;
            // same ascending-feature accumulation order as the reference
            acc0 += zrA.x * w2[2 * st]; acc0 += ziA.x * w2[2 * st + 1];
            acc1 += zrA.y * w2[2 * st]; acc1 += ziA.y * w2[2 * st + 1];
            acc2 += zrB.x * w2[2 * st]; acc2 += ziB.x * w2[2 * st + 1];
            acc3 += zrB.y * w2[2 * st]; acc3 += ziB.y * w2[2 * st + 1];
        }

        // Store 4 token rows (16 KB per block-iteration), plain dwordx2.
        v2f* obase = reinterpret_cast<v2f*>(out + (size_t)(TB * g) * EMBED) + t;
        obase[0 * (EMBED / 2)] = acc0;
        obase[1 * (EMBED / 2)] = acc1;
        obase[2 * (EMBED / 2)] = acc2;
        obase[3 * (EMBED / 2)] = acc3;

        // ---- rotate pipeline registers ----
        ca = n0; cb = n1; cc = n2; cd = n3;
        ids = nids;
    }
}

extern "C" void kernel_launch(void* const* d_in, const int* in_sizes, int n_in,
                              void* d_out, int out_size, void* d_ws, size_t ws_size,
                              hipStream_t stream) {
    const int*   tok   = (const int*)d_in[0];
    const float* ctab  = (const float*)d_in[1];
    const float* W     = (const float*)d_in[2];
    const float* scale = (const float*)d_in[3];
    float*       out   = (float*)d_out;

    FractalEmbedding_30365418782757_kernel<<<GRID, BLOCK, 0, stream>>>(tok, ctab, W, scale, out);
}